// Round 1
// baseline (257.275 us; speedup 1.0000x reference)
//
#include <hip/hip_runtime.h>
#include <math.h>

// SPLoss: fused CE (log-softmax + gather) -> exact quantile (radix select) ->
// power reweight -> mean.  B=32768, C=1000 fp32.
//
// ws layout:
//   [0 .. B)            float   ce per-sample loss
//   [B .. B+256)        uint    radix histogram (256 bins)
//   [B+256 ..)          uint    state: 0=prefix 1=k 2=lambda(f32) 3=exponent(f32) 4=acc(f32)

__device__ __forceinline__ unsigned f2u(float f) {
    unsigned u = __float_as_uint(f);
    return (u & 0x80000000u) ? ~u : (u | 0x80000000u);
}
__device__ __forceinline__ float u2f(unsigned u) {
    unsigned b = (u & 0x80000000u) ? (u & 0x7FFFFFFFu) : ~u;
    return __uint_as_float(b);
}

// One wave (64 lanes) per row: online softmax (m,s), then shuffle-combine.
__global__ void ce_kernel(const float* __restrict__ x, const int* __restrict__ tgt,
                          const int* __restrict__ epoch_p, float* __restrict__ ce,
                          unsigned* __restrict__ hist, unsigned* __restrict__ state,
                          int B, int C)
{
    int tid = threadIdx.x;
    if (blockIdx.x == 0) {
        // init hist + state for the later passes (ws is poisoned 0xAA each call)
        if (tid < 256) hist[tid] = 0u;
        if (tid == 0) {
            int e = epoch_p[0];
            double nr; int qt;
            if (e <= 25)      { nr = 0.7; qt = 2; }
            else if (e <= 75) { nr = 0.8; qt = 0; }
            else if (e <= 95) { nr = 0.9; qt = 0; }
            else              { nr = 1.0; qt = 0; }
            long long k = (long long)((double)B * nr);   // Python int() truncation
            if (k > (long long)B - 1) k = B - 1;         // jnp clamps OOB index
            state[0] = 0u;                               // radix prefix
            state[1] = (unsigned)k;                      // remaining rank
            ((float*)state)[3] = 1.0f / (float)(qt - 1); // exponent (+1 or -1)
            ((float*)state)[4] = 0.0f;                   // mean accumulator
        }
    }

    int lane = tid & 63;
    int row  = blockIdx.x * 4 + (tid >> 6);   // 4 waves per 256-thread block
    if (row >= B) return;

    const float* rp = x + (size_t)row * C;
    int C4 = C >> 2;
    float m = -INFINITY, s = 0.0f;

    const float4* p4 = (const float4*)rp;     // row stride 4000 B: 16-B aligned
    for (int i = lane; i < C4; i += 64) {
        float4 v = p4[i];
        float mx = fmaxf(fmaxf(v.x, v.y), fmaxf(v.z, v.w));
        if (mx > m) { s *= expf(m - mx); m = mx; }
        s += expf(v.x - m) + expf(v.y - m) + expf(v.z - m) + expf(v.w - m);
    }
    for (int i = (C4 << 2) + lane; i < C; i += 64) {   // remainder (C%4)
        float v = rp[i];
        if (v > m) { s *= expf(m - v); m = v; }
        s += expf(v - m);
    }

    // wave-wide (m,s) combine
    for (int off = 32; off > 0; off >>= 1) {
        float mo = __shfl_down(m, off, 64);
        float so = __shfl_down(s, off, 64);
        float nm = fmaxf(m, mo);
        float a = (m  == nm) ? s  : s  * expf(m  - nm);  // guards -inf - -inf = NaN
        float b = (mo == nm) ? so : so * expf(mo - nm);
        m = nm; s = a + b;
    }

    if (lane == 0) {
        int t = tgt[row];
        ce[row] = (m + logf(s)) - rp[t];
    }
}

// 8-bit radix-select histogram pass (high byte -> low byte).
__global__ void hist_kernel(const float* __restrict__ ce, unsigned* __restrict__ hist,
                            const unsigned* __restrict__ state, int B, int pass)
{
    __shared__ unsigned lh[256];
    int tid = threadIdx.x;
    lh[tid] = 0u;
    __syncthreads();

    int shift = 24 - 8 * pass;
    unsigned prefix = state[0];
    unsigned hm = (pass == 0) ? 0u : (0xFFFFFFFFu << (shift + 8));

    for (int i = blockIdx.x * blockDim.x + tid; i < B; i += gridDim.x * blockDim.x) {
        unsigned u = f2u(ce[i]);
        if ((u & hm) == (prefix & hm))
            atomicAdd(&lh[(u >> shift) & 0xFFu], 1u);
    }
    __syncthreads();
    if (lh[tid]) atomicAdd(&hist[tid], lh[tid]);
}

// Single-block scan: pick the bucket holding rank k, update prefix, zero hist.
__global__ void scan_kernel(unsigned* __restrict__ hist, unsigned* __restrict__ state, int pass)
{
    __shared__ unsigned h[256];
    int tid = threadIdx.x;
    h[tid] = hist[tid];
    __syncthreads();
    hist[tid] = 0u;                       // ready for next pass
    if (tid == 0) {
        unsigned k = state[1];
        unsigned cum = 0;
        int shift = 24 - 8 * pass;
        int bucket = 255;
        for (int i = 0; i < 256; ++i) {
            unsigned c = h[i];
            if (cum + c > k) { bucket = i; break; }
            cum += c;
        }
        state[1] = k - cum;
        unsigned prefix = state[0] | ((unsigned)bucket << shift);
        state[0] = prefix;
        if (pass == 3) ((float*)state)[2] = u2f(prefix);   // exact k-th smallest
    }
}

// v_t = (1 - ce/lambda)^exp; 0 past threshold; cap 10; accumulate ce*v.
__global__ void reduce_kernel(const float* __restrict__ ce, unsigned* __restrict__ state, int B)
{
    float lam  = ((const float*)state)[2];
    float expo = ((const float*)state)[3];
    float* acc = &((float*)state)[4];

    float part = 0.0f;
    for (int i = blockIdx.x * blockDim.x + threadIdx.x; i < B; i += gridDim.x * blockDim.x) {
        float c = ce[i];
        float base = 1.0f - c / lam;
        float v = (expo == 1.0f) ? base : powf(base, expo);
        if (c >= lam)       v = 0.0f;
        else if (v >= 10.f) v = 10.0f;
        part += c * v;
    }
    for (int off = 32; off > 0; off >>= 1) part += __shfl_down(part, off, 64);

    __shared__ float wsum[4];
    int lane = threadIdx.x & 63, w = threadIdx.x >> 6;
    if (lane == 0) wsum[w] = part;
    __syncthreads();
    if (threadIdx.x == 0) {
        float t = 0.0f;
        int nw = (int)(blockDim.x >> 6);
        for (int i = 0; i < nw; ++i) t += wsum[i];
        atomicAdd(acc, t);
    }
}

__global__ void final_kernel(const unsigned* __restrict__ state, float* __restrict__ out, int B)
{
    out[0] = ((const float*)state)[4] / (float)B;
}

extern "C" void kernel_launch(void* const* d_in, const int* in_sizes, int n_in,
                              void* d_out, int out_size, void* d_ws, size_t ws_size,
                              hipStream_t stream)
{
    const float* x     = (const float*)d_in[0];
    const int*   tgt   = (const int*)d_in[1];
    const int*   epoch = (const int*)d_in[2];
    int B = in_sizes[1];
    int C = in_sizes[0] / B;

    float*    ce    = (float*)d_ws;
    unsigned* hist  = (unsigned*)((char*)d_ws + (size_t)B * 4);
    unsigned* state = hist + 256;

    int ceBlocks = (B + 3) / 4;                       // 4 rows (waves) per block
    ce_kernel<<<ceBlocks, 256, 0, stream>>>(x, tgt, epoch, ce, hist, state, B, C);

    for (int pass = 0; pass < 4; ++pass) {
        hist_kernel<<<128, 256, 0, stream>>>(ce, hist, state, B, pass);
        scan_kernel<<<1, 256, 0, stream>>>(hist, state, pass);
    }

    reduce_kernel<<<128, 256, 0, stream>>>(ce, state, B);
    final_kernel<<<1, 1, 0, stream>>>(state, (float*)d_out, B);
}

// Round 2
// 255.258 us; speedup vs baseline: 1.0079x; 1.0079x over previous
//
#include <hip/hip_runtime.h>
#include <math.h>

// SPLoss fused single-kernel: CE (online log-softmax + gather) -> exact
// 4-pass radix select for the quantile -> power reweight -> mean.
// B=32768 rows, C=1000 classes, fp32.
//
// Structure: 2048 blocks x 1024 threads, one wave (64 lanes) per row.
// ce bits (monotone float->uint map) stored via agent-scope atomics so the
// last block (ticket pattern) can read them coherently across XCDs, then the
// last block does the select + reduce entirely from registers/LDS.
//
// ws layout: [0..B) uint ce bits, [B] uint ticket counter (memset to 0).

#define BLOCK 1024
#define WPB   16   // waves per block = rows per block

__device__ __forceinline__ unsigned f2u(float f) {
    unsigned u = __float_as_uint(f);
    return (u & 0x80000000u) ? ~u : (u | 0x80000000u);
}
__device__ __forceinline__ float u2f(unsigned u) {
    unsigned b = (u & 0x80000000u) ? (u & 0x7FFFFFFFu) : ~u;
    return __uint_as_float(b);
}

__global__ __launch_bounds__(BLOCK) void sploss_kernel(
        const float* __restrict__ x, const int* __restrict__ tgt,
        const int* __restrict__ epoch_p,
        unsigned* __restrict__ ceu, unsigned* __restrict__ counter,
        float* __restrict__ out, int B, int C)
{
    const int tid  = threadIdx.x;
    const int lane = tid & 63;
    const int wave = tid >> 6;

    // ---------------- phase 1: per-row CE (one wave per row) ----------------
    int row = blockIdx.x * WPB + wave;
    if (row < B) {
        const float* rp = x + (size_t)row * C;
        int t = tgt[row];
        float tv = rp[t];                      // uniform addr within wave: 1 load
        float m = -INFINITY, s = 0.0f;
        const float4* p4 = (const float4*)rp;  // row stride 4000 B is 16-B aligned
        int C4 = C >> 2;
        for (int i = lane; i < C4; i += 64) {
            float4 v = p4[i];
            float mx = fmaxf(fmaxf(v.x, v.y), fmaxf(v.z, v.w));
            if (mx > m) { s *= __expf(m - mx); m = mx; }
            s += __expf(v.x - m) + __expf(v.y - m) + __expf(v.z - m) + __expf(v.w - m);
        }
        for (int i = (C4 << 2) + lane; i < C; i += 64) {   // C%4 remainder
            float v = rp[i];
            if (v > m) { s *= __expf(m - v); m = v; }
            s += __expf(v - m);
        }
        // wave-wide (m,s) combine
        for (int off = 32; off > 0; off >>= 1) {
            float mo = __shfl_down(m, off, 64);
            float so = __shfl_down(s, off, 64);
            float nm = fmaxf(m, mo);
            float a = (m  == nm) ? s  : s  * __expf(m  - nm);
            float b = (mo == nm) ? so : so * __expf(mo - nm);
            m = nm; s = a + b;
        }
        if (lane == 0) {
            float cev = (m + __logf(s)) - tv;
            // agent-scope store -> coherence point (safe cross-XCD read later)
            __hip_atomic_store(&ceu[row], f2u(cev),
                               __ATOMIC_RELAXED, __HIP_MEMORY_SCOPE_AGENT);
        }
    }

    // ---------------- ticket: last block carries on ----------------
    __shared__ unsigned s_old;
    __syncthreads();   // emits s_waitcnt vmcnt(0): all ce stores are visible
    if (tid == 0)
        s_old = __hip_atomic_fetch_add(counter, 1u,
                                       __ATOMIC_ACQ_REL, __HIP_MEMORY_SCOPE_AGENT);
    __syncthreads();
    if (s_old != gridDim.x - 1) return;

    // ---------------- phase 2: select + reduce (one block) ----------------
    // schedule (mirrors _adjust_N_ratio_q_t; epoch read on-device)
    int e = epoch_p[0];
    double nr; int qt;
    if (e <= 25)      { nr = 0.7; qt = 2; }
    else if (e <= 75) { nr = 0.8; qt = 0; }
    else if (e <= 95) { nr = 0.9; qt = 0; }
    else              { nr = 1.0; qt = 0; }
    long long kk = (long long)((double)B * nr);   // Python int() truncation
    if (kk > (long long)B - 1) kk = (long long)B - 1;  // jnp index clamp
    const bool inv = (qt != 2);                   // exponent -1 vs +1

    // load all ce bits once into registers: 32 per thread (B == 32*BLOCK)
    unsigned uv[32];
#pragma unroll
    for (int j = 0; j < 32; ++j) {
        int i = tid + j * BLOCK;
        uv[j] = (i < B) ? __hip_atomic_load(&ceu[i], __ATOMIC_RELAXED,
                                            __HIP_MEMORY_SCOPE_AGENT)
                        : 0xFFFFFFFFu;
    }

    __shared__ unsigned lh[256];
    __shared__ unsigned s_prefix, s_k;
    if (tid == 0) { s_prefix = 0u; s_k = (unsigned)kk; }

    for (int p = 0; p < 4; ++p) {
        if (tid < 256) lh[tid] = 0u;
        __syncthreads();
        const int shift = 24 - 8 * p;
        const unsigned hm   = (p == 0) ? 0u : (0xFFFFFFFFu << (shift + 8));
        const unsigned pref = s_prefix;
#pragma unroll
        for (int j = 0; j < 32; ++j) {
            unsigned u = uv[j];
            if ((u & hm) == (pref & hm))
                atomicAdd(&lh[(u >> shift) & 255u], 1u);
        }
        __syncthreads();
        if (wave == 0) {   // wave-parallel bucket find: lane i owns bins 4i..4i+3
            unsigned c0 = lh[4 * lane], c1 = lh[4 * lane + 1];
            unsigned c2 = lh[4 * lane + 2], c3 = lh[4 * lane + 3];
            unsigned c4 = c0 + c1 + c2 + c3;
            unsigned incl = c4;
            for (int off = 1; off < 64; off <<= 1) {
                unsigned tt = __shfl_up(incl, off, 64);
                if (lane >= off) incl += tt;
            }
            unsigned excl = incl - c4;
            unsigned kr = s_k;
            unsigned long long bm = __ballot(excl <= kr && kr < excl + c4);
            int L = __ffsll(bm) - 1;
            if (lane == L) {
                unsigned rem = kr - excl;
                int b; unsigned cum;
                if      (rem < c0)           { b = 0; cum = 0; }
                else if (rem < c0 + c1)      { b = 1; cum = c0; }
                else if (rem < c0 + c1 + c2) { b = 2; cum = c0 + c1; }
                else                         { b = 3; cum = c0 + c1 + c2; }
                s_k = rem - cum;
                s_prefix = pref | ((unsigned)(4 * lane + b) << shift);
            }
        }
        __syncthreads();
    }

    // reweight + mean, straight from registers
    const float lam = u2f(s_prefix);   // exact k-th smallest ce
    float part = 0.0f;
#pragma unroll
    for (int j = 0; j < 32; ++j) {
        int i = tid + j * BLOCK;
        if (i >= B) continue;
        float c = u2f(uv[j]);
        float base = 1.0f - c / lam;
        float v = inv ? (1.0f / base) : base;   // q_t in {2,0} -> exponent +/-1
        if (c >= lam)       v = 0.0f;
        else if (v >= 10.f) v = 10.0f;
        part += c * v;
    }
    for (int off = 32; off > 0; off >>= 1) part += __shfl_down(part, off, 64);
    __shared__ float wsum[WPB];
    if (lane == 0) wsum[wave] = part;
    __syncthreads();
    if (tid == 0) {
        float tot = 0.0f;
        for (int i = 0; i < WPB; ++i) tot += wsum[i];
        out[0] = tot / (float)B;
    }
}

extern "C" void kernel_launch(void* const* d_in, const int* in_sizes, int n_in,
                              void* d_out, int out_size, void* d_ws, size_t ws_size,
                              hipStream_t stream)
{
    const float* x     = (const float*)d_in[0];
    const int*   tgt   = (const int*)d_in[1];
    const int*   epoch = (const int*)d_in[2];
    int B = in_sizes[1];
    int C = in_sizes[0] / B;

    unsigned* ceu     = (unsigned*)d_ws;
    unsigned* counter = ceu + B;

    hipMemsetAsync(counter, 0, sizeof(unsigned), stream);   // capture-safe

    int blocks = (B + WPB - 1) / WPB;
    sploss_kernel<<<blocks, BLOCK, 0, stream>>>(x, tgt, epoch, ceu, counter,
                                                (float*)d_out, B, C);
}

// Round 3
// 227.020 us; speedup vs baseline: 1.1333x; 1.1244x over previous
//
#include <hip/hip_runtime.h>
#include <math.h>

// SPLoss, 2-kernel: K1 = fused CE (log-softmax + gather), one wave per row,
// all-register row slice.  K2 = single-block exact radix select (quantile) +
// power reweight + mean, entirely from LDS.
// B=32768, C=1000, fp32.  Kernel boundary provides cross-XCD coherence.
//
// ws: [0..B) uint  ce bit-patterns (monotone float->uint map)

__device__ __forceinline__ unsigned f2u(float f) {
    unsigned u = __float_as_uint(f);
    return (u & 0x80000000u) ? ~u : (u | 0x80000000u);
}
__device__ __forceinline__ float u2f(unsigned u) {
    unsigned b = (u & 0x80000000u) ? (u & 0x7FFFFFFFu) : ~u;
    return __uint_as_float(b);
}

#define CE_WPB 4   // waves (rows) per 256-thread block

// One wave per row. C <= 1024 assumed (C=1000): up to 4 float4 per lane,
// loaded up-front -> no serial online-softmax dependency chain.
__global__ __launch_bounds__(256) void ce_kernel(
        const float* __restrict__ x, const int* __restrict__ tgt,
        unsigned* __restrict__ ceu, int B, int C)
{
    const int lane = threadIdx.x & 63;
    const int wave = threadIdx.x >> 6;
    const int row  = blockIdx.x * CE_WPB + wave;
    if (row >= B) return;

    const float* rp = x + (size_t)row * C;
    const int C4 = C >> 2;                 // 250 for C=1000 (C%4==0)
    const float4* p4 = (const float4*)rp;  // row stride 4000 B: 16-B aligned

    const float NEG = -INFINITY;
    float4 v0 = make_float4(NEG, NEG, NEG, NEG), v1 = v0, v2 = v0, v3 = v0;
    // independent predicated loads — all 4 issue before any use
    if (lane       < C4) v0 = p4[lane];
    if (lane +  64 < C4) v1 = p4[lane + 64];
    if (lane + 128 < C4) v2 = p4[lane + 128];
    if (lane + 192 < C4) v3 = p4[lane + 192];
    const float tv = rp[tgt[row]];         // wave-uniform address: 1 transaction

    float m = fmaxf(fmaxf(fmaxf(v0.x, v0.y), fmaxf(v0.z, v0.w)),
                    fmaxf(fmaxf(v1.x, v1.y), fmaxf(v1.z, v1.w)));
    m = fmaxf(m, fmaxf(fmaxf(v2.x, v2.y), fmaxf(v2.z, v2.w)));
    m = fmaxf(m, fmaxf(fmaxf(v3.x, v3.y), fmaxf(v3.z, v3.w)));
    for (int off = 32; off > 0; off >>= 1)
        m = fmaxf(m, __shfl_xor(m, off, 64));

    // __expf(-inf - m) == 0, so the -inf padding contributes nothing
    float s = __expf(v0.x - m) + __expf(v0.y - m) + __expf(v0.z - m) + __expf(v0.w - m)
            + __expf(v1.x - m) + __expf(v1.y - m) + __expf(v1.z - m) + __expf(v1.w - m)
            + __expf(v2.x - m) + __expf(v2.y - m) + __expf(v2.z - m) + __expf(v2.w - m)
            + __expf(v3.x - m) + __expf(v3.y - m) + __expf(v3.z - m) + __expf(v3.w - m);
    for (int off = 32; off > 0; off >>= 1)
        s += __shfl_xor(s, off, 64);

    if (lane == 0)
        ceu[row] = f2u((m + __logf(s)) - tv);
}

// Single block: stage all ce bits in LDS, 4-pass 8-bit radix select for the
// exact k-th smallest, then reweight + mean from LDS.
#define K2_T 1024
__global__ __launch_bounds__(K2_T) void select_kernel(
        const unsigned* __restrict__ ceu, const int* __restrict__ epoch_p,
        float* __restrict__ out, int B)
{
    __shared__ unsigned sv[32768];        // 128 KB of the 160 KB LDS
    __shared__ unsigned sh[256];
    __shared__ unsigned s_prefix, s_k;
    __shared__ float    s_wsum[K2_T / 64];

    const int tid  = threadIdx.x;
    const int lane = tid & 63;
    const int wave = tid >> 6;

    // stage ce bits: coalesced uint4 loads, 8 per thread, independent
    const uint4* c4 = (const uint4*)ceu;
    const int n4 = B >> 2;
    for (int i = tid; i < n4; i += K2_T) ((uint4*)sv)[i] = c4[i];

    // schedule (wave-uniform; mirrors _adjust_N_ratio_q_t)
    const int e = epoch_p[0];
    double nr; int qt;
    if (e <= 25)      { nr = 0.7; qt = 2; }
    else if (e <= 75) { nr = 0.8; qt = 0; }
    else if (e <= 95) { nr = 0.9; qt = 0; }
    else              { nr = 1.0; qt = 0; }
    const bool inv = (qt != 2);           // exponent 1/(qt-1) is +1 or -1
    if (tid == 0) {
        long long kk = (long long)((double)B * nr);   // Python int() truncation
        if (kk > (long long)B - 1) kk = (long long)B - 1;  // jnp index clamp
        s_prefix = 0u;
        s_k = (unsigned)kk;
    }
    __syncthreads();

    for (int p = 0; p < 4; ++p) {
        if (tid < 256) sh[tid] = 0u;
        __syncthreads();
        const int shift = 24 - 8 * p;
        const unsigned hm   = p ? (0xFFFFFFFFu << (shift + 8)) : 0u;
        const unsigned pref = s_prefix;
        for (int j = tid; j < B; j += K2_T) {          // 32 values/thread
            unsigned u = sv[j];
            if ((u & hm) == (pref & hm))
                atomicAdd(&sh[(u >> shift) & 255u], 1u);
        }
        __syncthreads();
        if (wave == 0) {   // wave-parallel bucket find: lane i owns bins 4i..4i+3
            unsigned c0 = sh[4 * lane], c1 = sh[4 * lane + 1];
            unsigned c2 = sh[4 * lane + 2], c3 = sh[4 * lane + 3];
            unsigned cw = c0 + c1 + c2 + c3;
            unsigned incl = cw;
            for (int off = 1; off < 64; off <<= 1) {
                unsigned t = __shfl_up(incl, off, 64);
                if (lane >= off) incl += t;
            }
            unsigned excl = incl - cw;
            unsigned kr = s_k;
            unsigned long long bm = __ballot(excl <= kr && kr < excl + cw);
            int L = __ffsll(bm) - 1;
            if (lane == L) {
                unsigned rem = kr - excl;
                int b; unsigned cum;
                if      (rem < c0)           { b = 0; cum = 0; }
                else if (rem < c0 + c1)      { b = 1; cum = c0; }
                else if (rem < c0 + c1 + c2) { b = 2; cum = c0 + c1; }
                else                         { b = 3; cum = c0 + c1 + c2; }
                s_k = rem - cum;
                s_prefix = pref | ((unsigned)(4 * lane + b) << shift);
            }
        }
        __syncthreads();
    }

    // reweight + mean from LDS
    const float lam = u2f(s_prefix);      // exact k-th smallest ce
    float part = 0.0f;
    for (int j = tid; j < B; j += K2_T) {
        float c = u2f(sv[j]);
        float base = 1.0f - c / lam;
        float v = inv ? (1.0f / base) : base;
        if (c >= lam)       v = 0.0f;
        else if (v >= 10.f) v = 10.0f;
        part += c * v;
    }
    for (int off = 32; off > 0; off >>= 1) part += __shfl_xor(part, off, 64);
    if (lane == 0) s_wsum[wave] = part;
    __syncthreads();
    if (tid == 0) {
        float tot = 0.0f;
        for (int i = 0; i < K2_T / 64; ++i) tot += s_wsum[i];
        out[0] = tot / (float)B;
    }
}

extern "C" void kernel_launch(void* const* d_in, const int* in_sizes, int n_in,
                              void* d_out, int out_size, void* d_ws, size_t ws_size,
                              hipStream_t stream)
{
    const float* x     = (const float*)d_in[0];
    const int*   tgt   = (const int*)d_in[1];
    const int*   epoch = (const int*)d_in[2];
    int B = in_sizes[1];
    int C = in_sizes[0] / B;

    unsigned* ceu = (unsigned*)d_ws;

    int ceBlocks = (B + CE_WPB - 1) / CE_WPB;
    ce_kernel<<<ceBlocks, 256, 0, stream>>>(x, tgt, ceu, B, C);
    select_kernel<<<1, K2_T, 0, stream>>>(ceu, epoch, (float*)d_out, B);
}

// Round 4
// 212.247 us; speedup vs baseline: 1.2121x; 1.0696x over previous
//
#include <hip/hip_runtime.h>
#include <math.h>

// SPLoss, 3-kernel:
//  K1 ce_kernel     : fused CE (log-softmax + gather), 1 wave/row, register slice.
//                     Block 0 also zeroes the global pass-0 histogram.
//  K2a hist0_kernel : pass-0 (high byte) histogram, 16 blocks, per-wave LDS
//                     privatization -> global merge.  (CE values concentrate in
//                     1-2 exponent buckets; single-CU LDS atomics serialized ~30k
//                     slots -- spreading across 16 CUs' LDS units kills that.)
//  K2b select_kernel: single block -- scan pass-0 hist, radix passes 1-3 from
//                     LDS-staged values (spread bins -> cheap atomics), then
//                     power reweight + mean.
// B=32768, C=1000, fp32. Kernel boundaries give cross-XCD coherence.
//
// ws: [0..B) uint ce bits (monotone float->uint), [B..B+256) uint ghist.

__device__ __forceinline__ unsigned f2u(float f) {
    unsigned u = __float_as_uint(f);
    return (u & 0x80000000u) ? ~u : (u | 0x80000000u);
}
__device__ __forceinline__ float u2f(unsigned u) {
    unsigned b = (u & 0x80000000u) ? (u & 0x7FFFFFFFu) : ~u;
    return __uint_as_float(b);
}

#define CE_WPB 4

__global__ __launch_bounds__(256) void ce_kernel(
        const float* __restrict__ x, const int* __restrict__ tgt,
        unsigned* __restrict__ ceu, unsigned* __restrict__ ghist, int B, int C)
{
    if (blockIdx.x == 0 && threadIdx.x < 256) ghist[threadIdx.x] = 0u;

    const int lane = threadIdx.x & 63;
    const int wave = threadIdx.x >> 6;
    const int row  = blockIdx.x * CE_WPB + wave;
    if (row >= B) return;

    const float* rp = x + (size_t)row * C;
    const int t = tgt[row];               // issue the dependent pair early
    const float tv = rp[t];               // wave-uniform address: 1 transaction

    const int C4 = C >> 2;                // 250 (C%4==0)
    const float4* p4 = (const float4*)rp; // row stride 4000 B: 16-B aligned
    const float NEG = -INFINITY;
    float4 v0 = make_float4(NEG, NEG, NEG, NEG), v1 = v0, v2 = v0, v3 = v0;
    if (lane       < C4) v0 = p4[lane];
    if (lane +  64 < C4) v1 = p4[lane + 64];
    if (lane + 128 < C4) v2 = p4[lane + 128];
    if (lane + 192 < C4) v3 = p4[lane + 192];

    float m = fmaxf(fmaxf(fmaxf(v0.x, v0.y), fmaxf(v0.z, v0.w)),
                    fmaxf(fmaxf(v1.x, v1.y), fmaxf(v1.z, v1.w)));
    m = fmaxf(m, fmaxf(fmaxf(v2.x, v2.y), fmaxf(v2.z, v2.w)));
    m = fmaxf(m, fmaxf(fmaxf(v3.x, v3.y), fmaxf(v3.z, v3.w)));
    for (int off = 32; off > 0; off >>= 1)
        m = fmaxf(m, __shfl_xor(m, off, 64));

    float s = __expf(v0.x - m) + __expf(v0.y - m) + __expf(v0.z - m) + __expf(v0.w - m)
            + __expf(v1.x - m) + __expf(v1.y - m) + __expf(v1.z - m) + __expf(v1.w - m)
            + __expf(v2.x - m) + __expf(v2.y - m) + __expf(v2.z - m) + __expf(v2.w - m)
            + __expf(v3.x - m) + __expf(v3.y - m) + __expf(v3.z - m) + __expf(v3.w - m);
    for (int off = 32; off > 0; off >>= 1)
        s += __shfl_xor(s, off, 64);

    if (lane == 0)
        ceu[row] = f2u((m + __logf(s)) - tv);
}

// Pass-0 histogram: 16 blocks x 512 thr, 4 values/thread (uint4), per-wave
// LDS hists (8 x 256), merged to ghist via global atomics.
__global__ __launch_bounds__(512) void hist0_kernel(
        const unsigned* __restrict__ ceu, unsigned* __restrict__ ghist, int B)
{
    __shared__ unsigned wh[8][256];
    const int tid  = threadIdx.x;
    const int wave = tid >> 6;

    #pragma unroll
    for (int j = 0; j < 4; ++j) wh[(tid * 4 + j) >> 8][(tid * 4 + j) & 255] = 0u;
    __syncthreads();

    const int i = blockIdx.x * 512 + tid;           // 16*512 uint4 == B
    if (i * 4 < B) {
        uint4 u = ((const uint4*)ceu)[i];
        atomicAdd(&wh[wave][u.x >> 24], 1u);
        atomicAdd(&wh[wave][u.y >> 24], 1u);
        atomicAdd(&wh[wave][u.z >> 24], 1u);
        atomicAdd(&wh[wave][u.w >> 24], 1u);
    }
    __syncthreads();

    if (tid < 256) {
        unsigned s = 0;
        #pragma unroll
        for (int w = 0; w < 8; ++w) s += wh[w][tid];
        if (s) atomicAdd(&ghist[tid], s);
    }
}

// Single block: pass-0 scan from ghist, passes 1-3 from LDS, reweight + mean.
#define K2_T 1024
__global__ __launch_bounds__(K2_T) void select_kernel(
        const unsigned* __restrict__ ceu, const unsigned* __restrict__ ghist,
        const int* __restrict__ epoch_p, float* __restrict__ out, int B)
{
    __shared__ unsigned sv[32768];     // 128 KB
    __shared__ unsigned sh[256];
    __shared__ unsigned s_prefix, s_k;
    __shared__ float    s_wsum[K2_T / 64];

    const int tid  = threadIdx.x;
    const int lane = tid & 63;
    const int wave = tid >> 6;

    // stage all ce bits (coalesced uint4, 8 per thread)
    const int n4 = B >> 2;
    for (int i = tid; i < n4; i += K2_T) ((uint4*)sv)[i] = ((const uint4*)ceu)[i];

    // schedule (mirrors _adjust_N_ratio_q_t)
    const int e = epoch_p[0];
    double nr; int qt;
    if (e <= 25)      { nr = 0.7; qt = 2; }
    else if (e <= 75) { nr = 0.8; qt = 0; }
    else if (e <= 95) { nr = 0.9; qt = 0; }
    else              { nr = 1.0; qt = 0; }
    const bool inv = (qt != 2);        // exponent 1/(qt-1) in {+1,-1}

    // pass 0: bucket find from the precomputed global histogram (wave 0)
    if (wave == 0) {
        long long kk = (long long)((double)B * nr);          // Python int()
        if (kk > (long long)B - 1) kk = (long long)B - 1;    // jnp index clamp
        uint4 g = ((const uint4*)ghist)[lane];               // bins 4L..4L+3
        unsigned c0 = g.x, c1 = g.y, c2 = g.z, c3 = g.w;
        unsigned cw = c0 + c1 + c2 + c3;
        unsigned incl = cw;
        for (int off = 1; off < 64; off <<= 1) {
            unsigned t = __shfl_up(incl, off, 64);
            if (lane >= off) incl += t;
        }
        unsigned excl = incl - cw;
        unsigned kr = (unsigned)kk;
        unsigned long long bm = __ballot(excl <= kr && kr < excl + cw);
        int L = __ffsll(bm) - 1;
        if (lane == L) {
            unsigned rem = kr - excl;
            int b; unsigned cum;
            if      (rem < c0)           { b = 0; cum = 0; }
            else if (rem < c0 + c1)      { b = 1; cum = c0; }
            else if (rem < c0 + c1 + c2) { b = 2; cum = c0 + c1; }
            else                         { b = 3; cum = c0 + c1 + c2; }
            s_k = rem - cum;
            s_prefix = (unsigned)(4 * L + b) << 24;
        }
    }
    __syncthreads();

    // passes 1-3 from LDS (bins spread across mantissa bytes -> cheap atomics)
    for (int p = 1; p < 4; ++p) {
        if (tid < 256) sh[tid] = 0u;
        __syncthreads();
        const int shift = 24 - 8 * p;
        const unsigned hm   = 0xFFFFFFFFu << (shift + 8);
        const unsigned pref = s_prefix;
        for (int j = tid; j < B; j += K2_T) {
            unsigned u = sv[j];
            if ((u & hm) == (pref & hm))
                atomicAdd(&sh[(u >> shift) & 255u], 1u);
        }
        __syncthreads();
        if (wave == 0) {
            unsigned c0 = sh[4 * lane], c1 = sh[4 * lane + 1];
            unsigned c2 = sh[4 * lane + 2], c3 = sh[4 * lane + 3];
            unsigned cw = c0 + c1 + c2 + c3;
            unsigned incl = cw;
            for (int off = 1; off < 64; off <<= 1) {
                unsigned t = __shfl_up(incl, off, 64);
                if (lane >= off) incl += t;
            }
            unsigned excl = incl - cw;
            unsigned kr = s_k;
            unsigned long long bm = __ballot(excl <= kr && kr < excl + cw);
            int L = __ffsll(bm) - 1;
            if (lane == L) {
                unsigned rem = kr - excl;
                int b; unsigned cum;
                if      (rem < c0)           { b = 0; cum = 0; }
                else if (rem < c0 + c1)      { b = 1; cum = c0; }
                else if (rem < c0 + c1 + c2) { b = 2; cum = c0 + c1; }
                else                         { b = 3; cum = c0 + c1 + c2; }
                s_k = rem - cum;
                s_prefix = pref | ((unsigned)(4 * lane + b) << shift);
            }
        }
        __syncthreads();
    }

    // reweight + mean from LDS
    const float lam = u2f(s_prefix);   // exact k-th smallest ce
    float part = 0.0f;
    for (int j = tid; j < B; j += K2_T) {
        float c = u2f(sv[j]);
        float base = 1.0f - c / lam;
        float v = inv ? (1.0f / base) : base;
        if (c >= lam)       v = 0.0f;
        else if (v >= 10.f) v = 10.0f;
        part += c * v;
    }
    for (int off = 32; off > 0; off >>= 1) part += __shfl_xor(part, off, 64);
    if (lane == 0) s_wsum[wave] = part;
    __syncthreads();
    if (tid == 0) {
        float tot = 0.0f;
        for (int i = 0; i < K2_T / 64; ++i) tot += s_wsum[i];
        out[0] = tot / (float)B;
    }
}

extern "C" void kernel_launch(void* const* d_in, const int* in_sizes, int n_in,
                              void* d_out, int out_size, void* d_ws, size_t ws_size,
                              hipStream_t stream)
{
    const float* x     = (const float*)d_in[0];
    const int*   tgt   = (const int*)d_in[1];
    const int*   epoch = (const int*)d_in[2];
    int B = in_sizes[1];
    int C = in_sizes[0] / B;

    unsigned* ceu   = (unsigned*)d_ws;
    unsigned* ghist = ceu + B;

    int ceBlocks = (B + CE_WPB - 1) / CE_WPB;
    ce_kernel<<<ceBlocks, 256, 0, stream>>>(x, tgt, ceu, ghist, B, C);
    hist0_kernel<<<16, 512, 0, stream>>>(ceu, ghist, B);
    select_kernel<<<1, K2_T, 0, stream>>>(ceu, ghist, epoch, (float*)d_out, B);
}